// Round 15
// baseline (35.979 us; speedup 1.0000x reference)
//
#include <hip/hip_runtime.h>

// out[b,o] = sum_{i,n} (Ps*tanh(k*(x + Ec*bm)) + bias) * coef
// bm = 1 + c*sg; c = -0.4*sigmoid(-10*(x-prev)); sg = 1/(1 + u*ee)
//   u = exp2(G*x) staged per (b,i); ee = exp2(G*Ec) in VGPR params
// tanh(a) = 1 - 2*r, r = 1/(1+exp2(kt*inner)); out = base[o] - 2*sum pc*r
//
// R11: R10 diagnostic (8x replica) showed VALUBusy 85% / occ 80% /
// 4.2M conflict cyc per pass => jointly VALU-issue-bound (trans = 16cyc
// issue each, 64 of 85 cyc/term) and LDS-pipe-bound (18 cyc/term + 4-way
// ih conflicts ~= 22us/CU). This kernel cuts VALU 78->44 cyc/term
// (1 trans left: basis exp2; gate exp2 via u*ee factorization; both rcps
// via magic-seed Newton) and LDS 18+conf -> 12 cyc/term conflict-free
// (params in 16 VGPRs -- no per-term b128; wave map 8 consecutive i0 x
// 8 n: banks 2*i0low/i0low distinct, n broadcasts).
// Predicted: VALU 9.4us/SIMD || LDS 10.2us/CU -> 15-19us wall.

#define GATE_C 14.426950408889634f   // 10*log2(e)
#define TANH_C 2.8853900817779268f   // 2*log2(e)

constexpr int B = 512, I = 128, O = 64, NB = 8, BT = 32, NS = 4;

__device__ __forceinline__ float rcp1(float d) {   // d>0, ~2.5e-3 rel
  float y = __int_as_float(0x7EF127EA - __float_as_int(d));
  return y * fmaf(-d, y, 2.f);
}
__device__ __forceinline__ float rcp2(float d) {   // d>0, ~1e-5 rel
  float y = __int_as_float(0x7EF127EA - __float_as_int(d));
  y = y * fmaf(-d, y, 2.f);
  return y * fmaf(-d, y, 2.f);
}

__global__ __launch_bounds__(1024) void fe_main(
    const float* __restrict__ x, const float* __restrict__ k,
    const float* __restrict__ Ec, const float* __restrict__ Ps,
    const float* __restrict__ bias, const float* __restrict__ coef,
    float* __restrict__ out)
{
  __shared__ float2 xc[BT][I];     // {x, c}  32 KB
  __shared__ float  ul[BT][I];     // u = exp2(G*x)  16 KB
  __shared__ float  racc[16][8];   // per-wave b-partials
  __shared__ float  red[4];        // base[o] partials (bh==0 waves)

  const int tid = threadIdx.x;
  const int o  = blockIdx.y;
  const int b0 = blockIdx.x * BT;
  const int n  = tid & 7;             // branch
  const int i0 = (tid >> 3) & 31;     // i-lane: slots i = i0 + 32s
  const int bh = tid >> 8;            // b-octet 0..3
  const int w  = tid >> 6;            // wave 0..15

  // ---- params -> 16 VGPRs (gathered once per block) ----
  float ec[NS], ee[NS], kt[NS], pc[NS];
  float pbase = 0.f;
  #pragma unroll
  for (int s = 0; s < NS; ++s) {
    const int g = ((i0 + 32 * s) * O + o) * NB + n;
    const float E = Ec[g], K = k[g], P = Ps[g], C = coef[g], Bs = bias[g];
    ec[s] = E;
    ee[s] = __builtin_amdgcn_exp2f(GATE_C * E);
    kt[s] = K * TANH_C;
    pc[s] = P * C;
    pbase += fmaf(Bs, C, pc[s]);
  }
  #pragma unroll
  for (int m = 1; m < 64; m <<= 1) pbase += __shfl_xor(pbase, m);
  if (bh == 0 && (tid & 63) == 0) red[w] = pbase;   // w<4 iff bh==0

  // ---- stage {x, c} and u (coalesced; hw trans fine: 4 elems/thread) ----
  for (int e = tid; e < BT * I; e += 1024) {
    const int bb = e >> 7, i = e & 127;
    const int bg = b0 + bb;
    const float xv = x[bg * I + i];
    const float pv = (bg == 0) ? 0.f : x[(bg - 1) * I + i];
    const float c = -0.4f * __builtin_amdgcn_rcpf(
        1.f + __builtin_amdgcn_exp2f(GATE_C * (xv - pv)));
    xc[bb][i] = make_float2(xv, c);
    ul[bb][i] = __builtin_amdgcn_exp2f(GATE_C * xv);
  }
  __syncthreads();

  // ---- main: 4 slots x 8 b-rows; 8 independent chains; 1 trans/term ----
  float acc[8];
  #pragma unroll
  for (int j = 0; j < 8; ++j) acc[j] = 0.f;

  #pragma unroll
  for (int s = 0; s < NS; ++s) {
    const int ii = i0 + 32 * s;
    #pragma unroll
    for (int j = 0; j < 8; ++j) {
      const int b = bh * 8 + j;
      const float2 v = xc[b][ii];                 // conflict-free b64
      const float  u = ul[b][ii];                 // conflict-free b32
      const float d1 = fmaf(u, ee[s], 1.f);       // 1 + u*ee
      const float sg = rcp1(d1);                  // sigmoid(-10(x+Ec))
      const float bm = fmaf(v.y, sg, 1.f);        // 1 + c*sg
      const float t  = kt[s] * fmaf(ec[s], bm, v.x);
      const float d2 = 1.f + __builtin_amdgcn_exp2f(t);
      acc[j] = fmaf(pc[s], rcp2(d2), acc[j]);     // += pc*r
    }
  }

  // ---- reduce: full-wave butterfly per b-row; lane0 stashes ----
  #pragma unroll
  for (int j = 0; j < 8; ++j) {
    float a = acc[j];
    a += __shfl_xor(a, 1);  a += __shfl_xor(a, 2);  a += __shfl_xor(a, 4);
    a += __shfl_xor(a, 8);  a += __shfl_xor(a, 16); a += __shfl_xor(a, 32);
    acc[j] = a;
  }
  if ((tid & 63) == 0) {
    #pragma unroll
    for (int j = 0; j < 8; ++j) racc[w][j] = acc[j];
  }
  __syncthreads();

  // ---- final: row tid = bh'*8+j; sum the 4 waves of that bh' ----
  if (tid < BT) {
    const int bb = tid >> 3, j = tid & 7;
    const float r = racc[bb * 4 + 0][j] + racc[bb * 4 + 1][j]
                  + racc[bb * 4 + 2][j] + racc[bb * 4 + 3][j];
    const float base = red[0] + red[1] + red[2] + red[3];
    out[(b0 + tid) * O + o] = fmaf(-2.f, r, base);
  }
}

extern "C" void kernel_launch(void* const* d_in, const int* in_sizes, int n_in,
                              void* d_out, int out_size, void* d_ws, size_t ws_size,
                              hipStream_t stream) {
  const float* x    = (const float*)d_in[0];
  const float* k    = (const float*)d_in[1];
  const float* Ec   = (const float*)d_in[2];
  const float* Ps   = (const float*)d_in[3];
  const float* bias = (const float*)d_in[4];
  const float* coef = (const float*)d_in[5];
  float* out = (float*)d_out;

  dim3 grid(B / BT, O);   // (16, 64) = 1024 blocks, 1024 threads each
  fe_main<<<grid, 1024, 0, stream>>>(x, k, Ec, Ps, bias, coef, out);
}

// Round 16
// 24.866 us; speedup vs baseline: 1.4469x; 1.4469x over previous
//
#include <hip/hip_runtime.h>

// out[b,o] = sum_{i,n} (Ps*tanh(k*(x + Ec*bm)) + bias) * coef
// bm = 1 + c*sg; c = -0.4*sigmoid(-10*(x-prev)); sg = 1/(1 + u*ee)
//   u = exp2(G*x) staged; ee = exp2(G*Ec) staged in params
// tanh(a) = 1 - 2*r, r = 1/(1+exp2(kt*inner)); out = base[o] - 2*sum pc*r
//
// R16: R8 skeleton (512 blocks x 1024thr, TILES=2 -- proven 25.8us, 85%
// VALUBusy at saturation, co-bound VALU 18.1us/SIMD ~ LDS 18.2us/CU).
// Cuts BOTH pipes:
//  - LDS 18->15 cyc/term: row-pair-packed xp{x_e,x_o,c_e,c_o}+up{u_e,u_o}
//    (b128+b64 per 2 terms) + param b128 amortized over the pair.
//    Lane map (n=tid&7, bpl=(tid>>3)&7 in-wave; bph=tid[6], ih=tid>>7):
//    xp/up stride 16B/8B over bpl -> quads 4bpl/2bpl distinct; params
//    n-broadcast. Conflict-free (R10 measured 4.2M conflict cyc in R8).
//  - VALU ~46->~25 cyc/term: 1 trans (basis exp2; gate via u*ee fma),
//    magic+Newton rcps, packed f32x2 across the row pair (v_pk_* ops,
//    params splat, pairs pre-packed in LDS so zero assembly movs).
//  - Reduction: ONE f32x2 acc/thread, 6 shfl + LDS stash (R11 had 48).

#define GATE_C 14.426950408889634f   // 10*log2(e)
#define TANH_C 2.8853900817779268f   // 2*log2(e)

typedef float f32x2 __attribute__((ext_vector_type(2)));
typedef float f32x4 __attribute__((ext_vector_type(4)));
typedef int   i32x2 __attribute__((ext_vector_type(2)));

constexpr int B = 512, I = 128, O = 64, NB = 8, BT = 32, TILES = 2;
constexpr int BP = BT / 2;   // 16 row-pairs per tile

__device__ __forceinline__ f32x2 pk_rcp1(f32x2 d) {   // d>0, ~1.2e-3 rel
  i32x2 yi = (i32x2)(0x7EF127EA) - __builtin_bit_cast(i32x2, d);
  f32x2 y = __builtin_bit_cast(f32x2, yi);
  return y * __builtin_elementwise_fma(-d, y, (f32x2)(2.f));
}
__device__ __forceinline__ f32x2 pk_rcp2(f32x2 d) {   // d>0, ~1.5e-6 rel
  i32x2 yi = (i32x2)(0x7EF127EA) - __builtin_bit_cast(i32x2, d);
  f32x2 y = __builtin_bit_cast(f32x2, yi);
  y = y * __builtin_elementwise_fma(-d, y, (f32x2)(2.f));
  return y * __builtin_elementwise_fma(-d, y, (f32x2)(2.f));
}

__global__ __launch_bounds__(1024, 4) void fe_main(
    const float* __restrict__ x, const float* __restrict__ k,
    const float* __restrict__ Ec, const float* __restrict__ Ps,
    const float* __restrict__ bias, const float* __restrict__ coef,
    float* __restrict__ out)
{
  __shared__ f32x4 pl[I][NB];      // {ec, ee, kt, pc}           16 KB
  __shared__ f32x4 xp[I][BP];      // {x_e, x_o, c_e, c_o}       32 KB
  __shared__ f32x2 up[I][BP];      // {u_e, u_o}                 16 KB
  __shared__ f32x2 racc[16][8];    // per-wave pair-sums          1 KB
  __shared__ float red[16];        // base[o] partials

  const int tid = threadIdx.x;
  const int o   = blockIdx.y;
  const int n   = tid & 7;              // in-wave: branch
  const int bpl = (tid >> 3) & 7;       // in-wave: row-pair low
  const int w   = tid >> 6;             // wave 0..15
  const int bp  = ((tid >> 6) & 1) * 8 + bpl;   // row-pair 0..15
  const int ih  = tid >> 7;             // i-octant 0..7 (wave bits 2:1)

  // ---- params for this o (once per block) + base[o] partial ----
  {
    const int i = tid >> 3, nn = tid & 7;
    const int g = (i * O + o) * NB + nn;
    const float E = Ec[g], K = k[g], P = Ps[g], C = coef[g], Bs = bias[g];
    const float pc = P * C;
    pl[i][nn] = (f32x4){E, __builtin_amdgcn_exp2f(GATE_C * E), K * TANH_C, pc};
    float pbase = fmaf(Bs, C, pc);
    #pragma unroll
    for (int m = 1; m < 64; m <<= 1) pbase += __shfl_xor(pbase, m);
    if ((tid & 63) == 0) red[w] = pbase;
  }

  for (int t = 0; t < TILES; ++t) {
    const int b0 = blockIdx.x * (BT * TILES) + t * BT;
    __syncthreads();   // params/red ready (t=0); racc/xp safe to reuse (t>0)

    // ---- stage row-pair-packed {x,c} and {u} (x is L2-resident) ----
    for (int e = tid; e < I * BP; e += 1024) {
      const int bq = e & 15, i = e >> 4;
      const int re = b0 + 2 * bq;
      const float xe = x[re * I + i];
      const float xo = x[(re + 1) * I + i];
      const float xm = (re == 0) ? 0.f : x[(re - 1) * I + i];
      const float ce = -0.4f * __builtin_amdgcn_rcpf(
          1.f + __builtin_amdgcn_exp2f(GATE_C * (xe - xm)));
      const float co = -0.4f * __builtin_amdgcn_rcpf(
          1.f + __builtin_amdgcn_exp2f(GATE_C * (xo - xe)));
      xp[i][bq] = (f32x4){xe, xo, ce, co};
      up[i][bq] = (f32x2){__builtin_amdgcn_exp2f(GATE_C * xe),
                          __builtin_amdgcn_exp2f(GATE_C * xo)};
    }
    __syncthreads();

    // ---- main: 16 i's x 1 row-pair, packed f32x2, 1 trans/term ----
    f32x2 acc = (f32x2)(0.f);
    #pragma unroll
    for (int it = 0; it < 16; ++it) {
      const int i = ih * 16 + it;
      const f32x4 p = pl[i][n];       // broadcast over n-lanes
      const f32x4 q = xp[i][bp];      // conflict-free b128
      const f32x2 u = up[i][bp];      // conflict-free b64
      const f32x2 x2 = q.lo, c2 = q.hi;
      const f32x2 d1 = __builtin_elementwise_fma(u, (f32x2)(p.y), (f32x2)(1.f));
      const f32x2 sg = pk_rcp1(d1);                       // sigmoid(-10(x+Ec))
      const f32x2 bm = __builtin_elementwise_fma(c2, sg, (f32x2)(1.f));
      const f32x2 inr = __builtin_elementwise_fma((f32x2)(p.x), bm, x2);
      const f32x2 tt = (f32x2)(p.z) * inr;
      f32x2 e2;
      e2.x = __builtin_amdgcn_exp2f(tt.x);
      e2.y = __builtin_amdgcn_exp2f(tt.y);
      const f32x2 r = pk_rcp2(e2 + (f32x2)(1.f));
      acc = __builtin_elementwise_fma((f32x2)(p.w), r, acc);
    }

    // ---- reduce over n (in-wave), stash per (wave, bpl) ----
    acc.x += __shfl_xor(acc.x, 1); acc.y += __shfl_xor(acc.y, 1);
    acc.x += __shfl_xor(acc.x, 2); acc.y += __shfl_xor(acc.y, 2);
    acc.x += __shfl_xor(acc.x, 4); acc.y += __shfl_xor(acc.y, 4);
    if (n == 0) racc[w][bpl] = acc;
    __syncthreads();

    // ---- final: 16 threads sum the 8 ih-waves of their row-pair ----
    if (tid < 16) {
      f32x2 s = (f32x2)(0.f);
      #pragma unroll
      for (int q8 = 0; q8 < 8; ++q8) s += racc[q8 * 2 + (tid >> 3)][tid & 7];
      float base = 0.f;
      #pragma unroll
      for (int q = 0; q < 16; ++q) base += red[q];
      out[(b0 + 2 * tid) * O + o]     = fmaf(-2.f, s.x, base);
      out[(b0 + 2 * tid + 1) * O + o] = fmaf(-2.f, s.y, base);
    }
  }
}

extern "C" void kernel_launch(void* const* d_in, const int* in_sizes, int n_in,
                              void* d_out, int out_size, void* d_ws, size_t ws_size,
                              hipStream_t stream) {
  const float* x    = (const float*)d_in[0];
  const float* k    = (const float*)d_in[1];
  const float* Ec   = (const float*)d_in[2];
  const float* Ps   = (const float*)d_in[3];
  const float* bias = (const float*)d_in[4];
  const float* coef = (const float*)d_in[5];
  float* out = (float*)d_out;

  dim3 grid(B / (BT * TILES), O);   // (8, 64) = 512 blocks (proven best)
  fe_main<<<grid, 1024, 0, stream>>>(x, k, Ec, Ps, bias, coef, out);
}